// Round 14
// baseline (36.015 us; speedup 1.0000x reference)
//
#include <hip/hip_runtime.h>
#include <hip/hip_bf16.h>

#define BATCH    512
#define IN_WIDTH 4096
#define OUT_F    4096
#define FAN_IN   128
#define BCHUNK   16                 // batches per LDS-resident slice
#define NBG      (BATCH / BCHUNK)   // 32
#define OBLK     512                // o-range per gather block
#define NOG      (OUT_F / OBLK)     // 8
#define ODD_BASE 65552u             // odd-row region base: 64 KiB + 16 B
#define SLICE_B  131088u            // 2048*32 + ODD_BASE-65536 + 2048*32

typedef float    v2f __attribute__((ext_vector_type(2)));
typedef uint32_t v4u __attribute__((ext_vector_type(4)));

// jenc: byte offset of row j in the parity-split slice.
// Even rows: [0, 64K) stride 32 (start dwords {0,8,16,24}); odd rows:
// [64K+16, 128K+16) (start dwords {4,12,20,28}) -> 8 start-bank classes.
__device__ __forceinline__ uint32_t jenc(uint32_t j) {
  return ((j >> 1) << 5) + (j & 1) * ODD_BASE;
}

// ---------------------------------------------------------------------------
// Kernel A+P fused: blocks [0,2048): transpose input[b][j] f32 ->
// inTg slices (parity-split layout, byte-identical to the LDS image).
// Blocks [2048,4096): pack idx+weight -> pk[o][f] = {jenc(j), bits(w)}.
// ---------------------------------------------------------------------------
__global__ __launch_bounds__(256) void k_prep(const float* __restrict__ in,
                                              const int* __restrict__ idx,
                                              const float* __restrict__ weight,
                                              char* __restrict__ inTg,
                                              uint2* __restrict__ pk) {
  __shared__ float tile[32][33];
  const int blk = blockIdx.x;
  const int t   = threadIdx.x;
  if (blk < 2048) {
    const int jt = (blk & 127) * 32;
    const int bt = (blk >> 7) * 32;
    const int tx = t & 31;          // j_local
    const int ty = t >> 5;          // 0..7
#pragma unroll
    for (int r = 0; r < 32; r += 8) {
      tile[ty + r][tx] = in[(size_t)(bt + ty + r) * IN_WIDTH + (jt + tx)];
    }
    __syncthreads();
#pragma unroll
    for (int r = 0; r < 32; r += 8) {
      const int b = bt + tx;
      const uint32_t j = jt + ty + r;
      __hip_bfloat16 hv = __float2bfloat16(tile[tx][ty + r]);
      *reinterpret_cast<uint16_t*>(
          inTg + (size_t)(b >> 4) * SLICE_B + jenc(j) + (b & 15) * 2) =
          *reinterpret_cast<const uint16_t*>(&hv);
    }
  } else {
    const int i = (blk - 2048) * 256 + t;       // 0 .. 524287
    uint2 e;
    e.x = jenc((uint32_t)idx[i]);
    e.y = __float_as_uint(weight[i]);
    pk[i] = e;
  }
}

// ---------------------------------------------------------------------------
// Kernel B: LDS-staged gather (R13 pipeline, parity-split layout).
// Staging via global_load_lds width=16 (slice is byte-identical in global),
// + one 16 B tail via ds_write. DS depth-4 pipeline, counted lgkmcnt(4),
// 4-slot rotating pk prefetch. pk.x already holds the LDS byte offset.
// ---------------------------------------------------------------------------
__global__ __launch_bounds__(1024, 4) void k_gather_lds(const char* __restrict__ inTg,
                                                        const uint2* __restrict__ pk,
                                                        const float* __restrict__ bias,
                                                        float* __restrict__ out) {
  extern __shared__ char lds[];
  const int og = blockIdx.x;
  const int bg = blockIdx.y;
  const int t  = threadIdx.x;

  // ---- stage 131088 B via direct global->LDS (wave-uniform dest + lane*16)
  {
    const char* src = inTg + (size_t)bg * SLICE_B;
#pragma unroll
    for (int i = 0; i < 8; ++i) {
      const char* g = src + i * 16384 + t * 16;            // per-lane global
      char* d = lds + ((t >> 6) << 10) + (i << 14);        // wave-uniform base
      __builtin_amdgcn_global_load_lds(
          (const __attribute__((address_space(1))) void*)g,
          (__attribute__((address_space(3))) void*)d, 16, 0, 0);
    }
    if (t == 0) {  // 16 B tail (second half of the last odd row)
      const v4u tail = *reinterpret_cast<const v4u*>(src + (SLICE_B - 16));
      *reinterpret_cast<v4u*>(lds + (SLICE_B - 16)) = tail;
    }
    asm volatile("s_waitcnt vmcnt(0)" ::: "memory");
  }
  __syncthreads();

  const int wv = t >> 6;
  const int l  = t & 63;
  const int o  = og * OBLK + wv * 32 + (l >> 1);  // 32 o per wave, 2 lanes/o
  const int p  = l & 1;                           // batch half (8 of 16)

  const uint32_t sb = (uint32_t)(size_t)lds + (uint32_t)(p * 16);

  const uint4* __restrict__ pko =
      reinterpret_cast<const uint4*>(pk + (size_t)o * FAN_IN);   // 64 entries

  v2f a0 = {0.f, 0.f}, a1 = {0.f, 0.f}, a2 = {0.f, 0.f}, a3 = {0.f, 0.f};

#define DSREAD(d, je) \
  asm volatile("ds_read_b128 %0, %1" : "=v"(d) : "v"(sb + (je)))

#define WAIT4() do { asm volatile("s_waitcnt lgkmcnt(4)" ::: "memory"); \
                     __builtin_amdgcn_sched_barrier(0); } while (0)
#define WAIT0() do { asm volatile("s_waitcnt lgkmcnt(0)" ::: "memory"); \
                     __builtin_amdgcn_sched_barrier(0); } while (0)

#define CONSUME(v, wbits)                                              \
  do {                                                                 \
    const float wf_ = __uint_as_float(wbits);                          \
    v2f w2_; w2_[0] = wf_; w2_[1] = wf_;                               \
    v2f x0_, x1_, x2_, x3_;                                            \
    x0_[0] = __uint_as_float((v)[0] << 16);                            \
    x0_[1] = __uint_as_float((v)[0] & 0xffff0000u);                    \
    x1_[0] = __uint_as_float((v)[1] << 16);                            \
    x1_[1] = __uint_as_float((v)[1] & 0xffff0000u);                    \
    x2_[0] = __uint_as_float((v)[2] << 16);                            \
    x2_[1] = __uint_as_float((v)[2] & 0xffff0000u);                    \
    x3_[0] = __uint_as_float((v)[3] << 16);                            \
    x3_[1] = __uint_as_float((v)[3] & 0xffff0000u);                    \
    a0 += x0_ * w2_; a1 += x1_ * w2_; a2 += x2_ * w2_; a3 += x3_ * w2_;\
  } while (0)

  // q slots: slot s holds pk group g with g%4==s; refill slot c%4 with
  // group c+4 at iteration c (w's copied out at issue time).
  uint4 q0a = pko[0], q0b = pko[1];   // g0
  uint4 q1a = pko[2], q1b = pko[3];   // g1
  uint4 q2a = pko[4], q2b = pko[5];   // g2
  uint4 q3a = pko[6], q3b = pko[7];   // g3

  v4u vA0, vA1, vA2, vA3, vB0, vB1, vB2, vB3;
  uint32_t wA0, wA1, wA2, wA3, wB0, wB1, wB2, wB3;

  DSREAD(vA0, q0a.x); DSREAD(vA1, q0a.z); DSREAD(vA2, q0b.x); DSREAD(vA3, q0b.z);
  wA0 = q0a.y; wA1 = q0a.w; wA2 = q0b.y; wA3 = q0b.w;

#define STEP(Cc, QI0, QI1, QR0, QR1,                                   \
             VC0, VC1, VC2, VC3, WC0, WC1, WC2, WC3,                   \
             VI0, VI1, VI2, VI3, WI0, WI1, WI2, WI3)                   \
  do {                                                                 \
    DSREAD(VI0, QI0.x); DSREAD(VI1, QI0.z);                            \
    DSREAD(VI2, QI1.x); DSREAD(VI3, QI1.z);                            \
    WI0 = QI0.y; WI1 = QI0.w; WI2 = QI1.y; WI3 = QI1.w;                \
    {                                                                  \
      const int gn_ = ((Cc) + 4 > 31) ? 31 : ((Cc) + 4);               \
      QR0 = pko[2 * gn_];                                              \
      QR1 = pko[2 * gn_ + 1];                                          \
    }                                                                  \
    WAIT4();                                                           \
    CONSUME(VC0, WC0); CONSUME(VC1, WC1);                              \
    CONSUME(VC2, WC2); CONSUME(VC3, WC3);                              \
  } while (0)

#define STEP_A(Cc, QI0, QI1, QR0, QR1)                                   \
  STEP(Cc, QI0, QI1, QR0, QR1,                                           \
       vA0, vA1, vA2, vA3, wA0, wA1, wA2, wA3,                           \
       vB0, vB1, vB2, vB3, wB0, wB1, wB2, wB3)
#define STEP_B(Cc, QI0, QI1, QR0, QR1)                                   \
  STEP(Cc, QI0, QI1, QR0, QR1,                                           \
       vB0, vB1, vB2, vB3, wB0, wB1, wB2, wB3,                           \
       vA0, vA1, vA2, vA3, wA0, wA1, wA2, wA3)

#pragma unroll 1
  for (int cb = 0; cb < 28; cb += 4) {
    STEP_A(cb + 0, q1a, q1b, q0a, q0b);
    STEP_B(cb + 1, q2a, q2b, q1a, q1b);
    STEP_A(cb + 2, q3a, q3b, q2a, q2b);
    STEP_B(cb + 3, q0a, q0b, q3a, q3b);
  }
  STEP_A(28, q1a, q1b, q0a, q0b);
  STEP_B(29, q2a, q2b, q1a, q1b);
  STEP_A(30, q3a, q3b, q2a, q2b);
  // after c=30: A consumed g30, B holds g31 in flight
  WAIT0();
  CONSUME(vB0, wB0); CONSUME(vB1, wB1); CONSUME(vB2, wB2); CONSUME(vB3, wB3);

  const float bz = bias[o];
  const float r[8] = {a0[0], a0[1], a1[0], a1[1], a2[0], a2[1], a3[0], a3[1]};
  // out[b][o], b = bg*16 + p*8 + i ; per store a wave covers 2 x 128 B rows
  const size_t obase = (size_t)(bg * BCHUNK + p * 8) * OUT_F + o;
#pragma unroll
  for (int i = 0; i < 8; ++i) out[obase + (size_t)i * OUT_F] = r[i] + bz;

#undef STEP_B
#undef STEP_A
#undef STEP
#undef CONSUME
#undef WAIT4
#undef WAIT0
#undef DSREAD
}

extern "C" void kernel_launch(void* const* d_in, const int* in_sizes, int n_in,
                              void* d_out, int out_size, void* d_ws, size_t ws_size,
                              hipStream_t stream) {
  const float* input  = (const float*)d_in[0];   // [512][4096] f32
  const float* weight = (const float*)d_in[1];   // [4096][128] f32
  const float* bias   = (const float*)d_in[2];   // [4096]      f32
  const int*   idx    = (const int*)d_in[3];     // [4096][128] int32
  float* out = (float*)d_out;                    // [512][4096] f32

  // ws: inTg (parity-split slices, 32 x 131088 B ~= 4.0 MB) | pk at +6 MB
  char*  inTg = (char*)d_ws;
  uint2* pk   = (uint2*)((char*)d_ws + 6u * 1024 * 1024);

  k_prep<<<dim3(4096), dim3(256), 0, stream>>>(input, idx, weight, inTg, pk);
  k_gather_lds<<<dim3(NOG, NBG), dim3(1024), SLICE_B, stream>>>(inTg, pk, bias, out);
}